// Round 11
// baseline (76.465 us; speedup 1.0000x reference)
//
#include <hip/hip_runtime.h>

#define T_LEN 4096
#define D_IN 128
#define U_H 256
#define REC_MAXV 0.0625f

typedef __attribute__((ext_vector_type(4))) float f32x4;
typedef __attribute__((ext_vector_type(16))) float f32x16;
typedef __attribute__((ext_vector_type(2))) int int2v;
typedef long long i64;

template <bool HI>
__device__ __forceinline__ int pk8(float a, float b, int old) {
    return __builtin_amdgcn_cvt_pk_fp8_f32(a, b, old, HI);
}

__device__ __forceinline__ int reord32(int u) {
    int r = u & 31;
    return ((u >> 5) << 5) + (((r >> 2) & 1) << 4) + ((r >> 3) << 2) + (r & 3);
}

// -------- kernel 0 (fused prep): h, budR, boR, fp8 weight frags, loss0 -------
__global__ void k_pre(const float* __restrict__ xs, const float* __restrict__ We,
                      const float* __restrict__ be, const float* __restrict__ Wd,
                      const float* __restrict__ bd, const float* __restrict__ ud,
                      const float* __restrict__ Wo, const float* __restrict__ bo,
                      float* __restrict__ budR, float* __restrict__ boR,
                      char* __restrict__ WF8, float* __restrict__ part2) {
    __shared__ __align__(16) float hL[256];
    __shared__ float red[2];
    const int b = blockIdx.x, u = threadIdx.x;

    // ---- h[b][u] ----
    const f32x4* xr = (const f32x4*)(xs + ((size_t)b * T_LEN + (T_LEN - 1)) * D_IN);
    const f32x4* wr = (const f32x4*)(We + (size_t)u * D_IN);
    float s = 0.f;
#pragma unroll
    for (int i = 0; i < 32; ++i) {
        f32x4 a = xr[i], w = wr[i];
        s += a[0]*w[0] + a[1]*w[1] + a[2]*w[2] + a[3]*w[3];
    }
    s += be[u];
    s = fmaxf(s, 0.f);
    hL[u] = s;

    // ---- budR ----
    float udc = fminf(fmaxf(ud[u], -REC_MAXV), REC_MAXV);
    budR[(b << 8) + reord32(u)] = bd[u] + udc * s;

    // ---- boR (block 0 only) ----
    if (b == 0 && u < 128) boR[reord32(u)] = bo[u];

    // ---- weight frag packing (blocks 0..31) ----
    int gid = b * 256 + u;
    if (gid < 4096) {
        int f = gid >> 6, l = gid & 63;
        int ut = f >> 3, ks = f & 7;
        const float* src = Wd + (size_t)(ut * 32 + (l & 31)) * D_IN + ks * 16 + (l >> 5) * 8;
        int lo = pk8<false>(src[0], src[1], 0); lo = pk8<true>(src[2], src[3], lo);
        int hh = pk8<false>(src[4], src[5], 0); hh = pk8<true>(src[6], src[7], hh);
        *(int2v*)(WF8 + (size_t)gid * 8) = (int2v){lo, hh};
    } else if (gid < 8192) {
        int g = gid - 4096;
        int f = g >> 6, l = g & 63;
        int uk = f >> 2, dt = f & 3;
        const float* src = Wo + (size_t)(dt * 32 + (l & 31)) * U_H + uk * 16 + (l >> 5) * 8;
        int lo = pk8<false>(src[0], src[1], 0); lo = pk8<true>(src[2], src[3], lo);
        int hh = pk8<false>(src[4], src[5], 0); hh = pk8<true>(src[6], src[7], hh);
        *(int2v*)(WF8 + 32768 + (size_t)g * 8) = (int2v){lo, hh};
    }
    __syncthreads();

    // ---- t=0 loss term (threads 0..127 = output dim d) ----
    float v = 0.f;
    if (u < 128) {
        const f32x4* hr = (const f32x4*)hL;
        const f32x4* wo = (const f32x4*)(Wo + (size_t)u * U_H);
        float s2 = 0.f;
#pragma unroll
        for (int i = 0; i < 64; ++i) {
            f32x4 a = hr[i], w = wo[i];
            s2 += a[0]*w[0] + a[1]*w[1] + a[2]*w[2] + a[3]*w[3];
        }
        s2 += bo[u];
        float x = xs[((size_t)b * T_LEN + T_LEN - 1) * D_IN + u];
        float diff = x - s2;
        v = diff * diff;
    }
#pragma unroll
    for (int o = 32; o > 0; o >>= 1) v += __shfl_down(v, o);
    if (u == 0) red[0] = v;
    if (u == 64) red[1] = v;
    __syncthreads();
    if (u == 0) part2[b] = red[0] + red[1];
}

// ---- phase-1 step for one ut: GEMM1 (2x4 MFMA chains) + bias/relu + pack ----
__device__ __forceinline__ void ph1(const char* lds, const float* budL,
                                    int lane, int hi, int ut,
                                    i64 x0, i64 x1, i64 x2, i64 x3,
                                    i64 x4, i64 x5, i64 x6, i64 x7,
                                    i64& dlo, i64& dhi) {
    f32x16 ca, cb;
#pragma unroll
    for (int i = 0; i < 16; ++i) { ca[i] = 0.f; cb[i] = 0.f; }
    const int base = (ut * 8) << 9;
    ca = __builtin_amdgcn_mfma_f32_32x32x16_fp8_fp8(*(const i64*)(lds + base + (0<<9) + (lane<<3)), x0, ca, 0,0,0);
    cb = __builtin_amdgcn_mfma_f32_32x32x16_fp8_fp8(*(const i64*)(lds + base + (1<<9) + (lane<<3)), x1, cb, 0,0,0);
    ca = __builtin_amdgcn_mfma_f32_32x32x16_fp8_fp8(*(const i64*)(lds + base + (2<<9) + (lane<<3)), x2, ca, 0,0,0);
    cb = __builtin_amdgcn_mfma_f32_32x32x16_fp8_fp8(*(const i64*)(lds + base + (3<<9) + (lane<<3)), x3, cb, 0,0,0);
    ca = __builtin_amdgcn_mfma_f32_32x32x16_fp8_fp8(*(const i64*)(lds + base + (4<<9) + (lane<<3)), x4, ca, 0,0,0);
    cb = __builtin_amdgcn_mfma_f32_32x32x16_fp8_fp8(*(const i64*)(lds + base + (5<<9) + (lane<<3)), x5, cb, 0,0,0);
    ca = __builtin_amdgcn_mfma_f32_32x32x16_fp8_fp8(*(const i64*)(lds + base + (6<<9) + (lane<<3)), x6, ca, 0,0,0);
    cb = __builtin_amdgcn_mfma_f32_32x32x16_fp8_fp8(*(const i64*)(lds + base + (7<<9) + (lane<<3)), x7, cb, 0,0,0);
    const float* bp = budL + ut * 32 + hi * 16;
    f32x16 c;
#pragma unroll
    for (int q = 0; q < 4; ++q) {
        f32x4 bq = *(const f32x4*)(bp + q * 4);
#pragma unroll
        for (int j = 0; j < 4; ++j)
            c[q * 4 + j] = fmaxf(ca[q * 4 + j] + cb[q * 4 + j] + bq[j], 0.f);
    }
    int d0 = pk8<false>(c[0],  c[1],  0); d0 = pk8<true>(c[2],  c[3],  d0);
    int d1 = pk8<false>(c[4],  c[5],  0); d1 = pk8<true>(c[6],  c[7],  d1);
    int d2 = pk8<false>(c[8],  c[9],  0); d2 = pk8<true>(c[10], c[11], d2);
    int d3 = pk8<false>(c[12], c[13], 0); d3 = pk8<true>(c[14], c[15], d3);
    int2v s = __builtin_amdgcn_permlane32_swap(d0, d1, false, false);
    int2v t = __builtin_amdgcn_permlane32_swap(d2, d3, false, false);
    dlo = __builtin_bit_cast(i64, s);
    dhi = __builtin_bit_cast(i64, t);
    __builtin_amdgcn_sched_barrier(0);
}

// ---- phase-2 step for one uk: 2 MFMAs into oA/oB (4-chain split by caller) --
__device__ __forceinline__ void ph2(const char* lds, int lane, int dc, int uk,
                                    i64 db, f32x16& oA, f32x16& oB) {
    i64 w0 = *(const i64*)(lds + 32768 + ((uk * 4 + dc * 2 + 0) << 9) + (lane << 3));
    i64 w1 = *(const i64*)(lds + 32768 + ((uk * 4 + dc * 2 + 1) << 9) + (lane << 3));
    oA = __builtin_amdgcn_mfma_f32_32x32x16_fp8_fp8(w0, db, oA, 0, 0, 0);
    oB = __builtin_amdgcn_mfma_f32_32x32x16_fp8_fp8(w1, db, oB, 0, 0, 0);
}

// ---------------- kernel 1: main fused pipeline (fp8, 1 tile/wave) -----------
// 2048 blocks x 256 threads (4 waves). One 32-row tile per wave, M=32.
// LDS 67.5KB -> 2 resident blocks/CU -> 4 GENERATIONS: gen i+1's X loads
// overlap gen i's compute (fixes the single-generation load-burst/compute
// serialization seen in R10: MfmaUtil 18% = 14us MFMA / 74us wall).
__global__ __launch_bounds__(256, 2) void k_main(
        const float* __restrict__ xs, const float* __restrict__ budR,
        const float* __restrict__ boR, const char* __restrict__ WF8,
        float* __restrict__ part) {
    __shared__ __align__(16) char lds[67200];
    const int tid = threadIdx.x;

    // stage 64KB fp8 weight frags + 1KB budR(b) + 512B boR
    for (int i = tid; i < 4096; i += 256)
        ((f32x4*)lds)[i] = ((const f32x4*)WF8)[i];
    const int b = blockIdx.x >> 5;          // 32 blocks per batch-entry
    if (tid < 64) ((f32x4*)(lds + 65536))[tid] = ((const f32x4*)(budR + b * 256))[tid];
    else if (tid < 96) ((f32x4*)(lds + 66560))[tid - 64] = ((const f32x4*)boR)[tid - 64];
    __syncthreads();

    const int wave = tid >> 6, lane = tid & 63;
    const int m = lane & 31, hi = lane >> 5;
    const float* xsb = xs + ((size_t)b << 19);
    const float* budL = (const float*)(lds + 65536);
    const float* boL  = (const float*)(lds + 66560);
    float* wsumf = (float*)(lds + 67072);

    const int tile = blockIdx.x * 4 + wave;
    const int t0 = (tile & 127) << 5;

    // ---- X row -> fp8 B-frags (8 named i64) ----
    const float* xrow = xsb + (size_t)(t0 + m) * 128 + hi * 8;
    i64 x0, x1, x2, x3, x4, x5, x6, x7;
    {
#define LDX(KS, XV)                                                      \
        {   f32x4 v0 = *(const f32x4*)(xrow + KS * 16);                  \
            f32x4 v1 = *(const f32x4*)(xrow + KS * 16 + 4);              \
            int lo = pk8<false>(v0[0], v0[1], 0); lo = pk8<true>(v0[2], v0[3], lo); \
            int hh = pk8<false>(v1[0], v1[1], 0); hh = pk8<true>(v1[2], v1[3], hh); \
            XV = __builtin_bit_cast(i64, (int2v){lo, hh}); }
        LDX(0, x0) LDX(1, x1) LDX(2, x2) LDX(3, x3)
        LDX(4, x4) LDX(5, x5) LDX(6, x6) LDX(7, x7)
#undef LDX
    }

    // ---- Phase 1: 8 ut-steps -> dec^T fp8 frags (16 named i64) ----
    i64 d0a, d0b, d1a, d1b, d2a, d2b, d3a, d3b;
    i64 d4a, d4b, d5a, d5b, d6a, d6b, d7a, d7b;
    ph1(lds, budL, lane, hi, 0, x0,x1,x2,x3,x4,x5,x6,x7, d0a, d0b);
    ph1(lds, budL, lane, hi, 1, x0,x1,x2,x3,x4,x5,x6,x7, d1a, d1b);
    ph1(lds, budL, lane, hi, 2, x0,x1,x2,x3,x4,x5,x6,x7, d2a, d2b);
    ph1(lds, budL, lane, hi, 3, x0,x1,x2,x3,x4,x5,x6,x7, d3a, d3b);
    ph1(lds, budL, lane, hi, 4, x0,x1,x2,x3,x4,x5,x6,x7, d4a, d4b);
    ph1(lds, budL, lane, hi, 5, x0,x1,x2,x3,x4,x5,x6,x7, d5a, d5b);
    ph1(lds, budL, lane, hi, 6, x0,x1,x2,x3,x4,x5,x6,x7, d6a, d6b);
    ph1(lds, budL, lane, hi, 7, x0,x1,x2,x3,x4,x5,x6,x7, d7a, d7b);

    // ---- Phase 2 (4 independent MFMA chains per dc) + fused loss epilogue ----
    const int t = t0 + m;
    const float sel = (t > 0) ? 1.f : 0.f;
    const float* trow = xsb + (size_t)((t > 0) ? t - 1 : 0) * 128;
    float lacc = 0.f;

#pragma unroll
    for (int dc = 0; dc < 2; ++dc) {
        f32x16 o0a, o0b, o1a, o1b;
#pragma unroll
        for (int i = 0; i < 16; ++i) { o0a[i] = 0.f; o0b[i] = 0.f; o1a[i] = 0.f; o1b[i] = 0.f; }
        ph2(lds, lane, dc,  0, d0a, o0a, o1a);
        ph2(lds, lane, dc,  1, d0b, o0b, o1b);
        ph2(lds, lane, dc,  2, d1a, o0a, o1a);
        ph2(lds, lane, dc,  3, d1b, o0b, o1b);
        ph2(lds, lane, dc,  4, d2a, o0a, o1a);
        ph2(lds, lane, dc,  5, d2b, o0b, o1b);
        ph2(lds, lane, dc,  6, d3a, o0a, o1a);
        ph2(lds, lane, dc,  7, d3b, o0b, o1b);
        ph2(lds, lane, dc,  8, d4a, o0a, o1a);
        ph2(lds, lane, dc,  9, d4b, o0b, o1b);
        ph2(lds, lane, dc, 10, d5a, o0a, o1a);
        ph2(lds, lane, dc, 11, d5b, o0b, o1b);
        ph2(lds, lane, dc, 12, d6a, o0a, o1a);
        ph2(lds, lane, dc, 13, d6b, o0b, o1b);
        ph2(lds, lane, dc, 14, d7a, o0a, o1a);
        ph2(lds, lane, dc, 15, d7b, o0b, o1b);
        __builtin_amdgcn_sched_barrier(0);
#pragma unroll
        for (int half = 0; half < 2; ++half) {
            const int dt = dc * 2 + half;
#pragma unroll
            for (int q = 0; q < 4; ++q) {
                f32x4 bv = *(const f32x4*)(boL + dt * 32 + hi * 16 + q * 4);
                f32x4 tg = *(const f32x4*)(trow + dt * 32 + q * 8 + hi * 4);
#pragma unroll
                for (int j = 0; j < 4; ++j) {
                    float ov = (half ? o1a[q * 4 + j] + o1b[q * 4 + j]
                                     : o0a[q * 4 + j] + o0b[q * 4 + j]) + bv[j];
                    float diff = tg[j] - ov;
                    lacc += sel * diff * diff;
                }
            }
        }
    }

    // ---- block-level reduction: ONE store per block, no atomic ----
#pragma unroll
    for (int o = 32; o > 0; o >>= 1) lacc += __shfl_down(lacc, o);
    if (lane == 0) wsumf[wave] = lacc;
    __syncthreads();
    if (tid == 0) {
        float s = 0.f;
#pragma unroll
        for (int i = 0; i < 4; ++i) s += wsumf[i];
        part[blockIdx.x] = s;
    }
}

// ---------------- kernel 2: final reduction (plain store, no atomic) ---------
__global__ void k_final(const float* __restrict__ part, const float* __restrict__ part2,
                        float* __restrict__ loss) {
    __shared__ float ws[16];
    const int tid = threadIdx.x;   // 1024
    float v = part[tid] + part[tid + 1024];
    if (tid < 64) v += part2[tid];
#pragma unroll
    for (int o = 32; o > 0; o >>= 1) v += __shfl_down(v, o);
    if ((tid & 63) == 0) ws[tid >> 6] = v;
    __syncthreads();
    if (tid == 0) {
        float s = 0.f;
#pragma unroll
        for (int i = 0; i < 16; ++i) s += ws[i];
        *loss = s * (1.f / 262144.f);
    }
}

extern "C" void kernel_launch(void* const* d_in, const int* in_sizes, int n_in,
                              void* d_out, int out_size, void* d_ws, size_t ws_size,
                              hipStream_t stream) {
    const float* xs = (const float*)d_in[0];
    const float* We = (const float*)d_in[1];
    const float* be = (const float*)d_in[2];
    // d_in[3] = ue (unused: encoder hidden state is always zero)
    const float* Wd = (const float*)d_in[4];
    const float* bd = (const float*)d_in[5];
    const float* ud = (const float*)d_in[6];
    const float* Wo = (const float*)d_in[7];
    const float* bo = (const float*)d_in[8];
    float* loss = (float*)d_out;

    char* ws = (char*)d_ws;
    float* budR  = (float*)(ws);             // 65536 B
    char*  WF8   = (char*)(ws + 65536);      // 65536 B (Wd frags, then Wo frags)
    float* boR   = (float*)(ws + 131072);    // 512 B
    float* part  = (float*)(ws + 131584);    // 8192 B (2048 block partials)
    float* part2 = (float*)(ws + 139776);    // 256 B  (64 loss0 partials)

    k_pre<<<64, 256, 0, stream>>>(xs, We, be, Wd, bd, ud, Wo, bo,
                                  budR, boR, WF8, part2);
    k_main<<<2048, 256, 0, stream>>>(xs, budR, boR, WF8, part);
    k_final<<<1, 1024, 0, stream>>>(part, part2, loss);
}

// Round 12
// 70.449 us; speedup vs baseline: 1.0854x; 1.0854x over previous
//
#include <hip/hip_runtime.h>

#define T_LEN 4096
#define D_IN 128
#define U_H 256
#define REC_MAXV 0.0625f

typedef __attribute__((ext_vector_type(4))) float f32x4;
typedef __attribute__((ext_vector_type(16))) float f32x16;
typedef __attribute__((ext_vector_type(2))) int int2v;
typedef long long i64;

template <bool HI>
__device__ __forceinline__ int pk8(float a, float b, int old) {
    return __builtin_amdgcn_cvt_pk_fp8_f32(a, b, old, HI);
}

__device__ __forceinline__ int reord32(int u) {
    int r = u & 31;
    return ((u >> 5) << 5) + (((r >> 2) & 1) << 4) + ((r >> 3) << 2) + (r & 3);
}

// -------- kernel 0 (fused prep): h, budR, boR, fp8 weight frags, loss0 -------
__global__ void k_pre(const float* __restrict__ xs, const float* __restrict__ We,
                      const float* __restrict__ be, const float* __restrict__ Wd,
                      const float* __restrict__ bd, const float* __restrict__ ud,
                      const float* __restrict__ Wo, const float* __restrict__ bo,
                      float* __restrict__ budR, float* __restrict__ boR,
                      char* __restrict__ WF8, float* __restrict__ part2) {
    __shared__ __align__(16) float hL[256];
    __shared__ float red[2];
    const int b = blockIdx.x, u = threadIdx.x;

    // ---- h[b][u] ----
    const f32x4* xr = (const f32x4*)(xs + ((size_t)b * T_LEN + (T_LEN - 1)) * D_IN);
    const f32x4* wr = (const f32x4*)(We + (size_t)u * D_IN);
    float s = 0.f;
#pragma unroll
    for (int i = 0; i < 32; ++i) {
        f32x4 a = xr[i], w = wr[i];
        s += a[0]*w[0] + a[1]*w[1] + a[2]*w[2] + a[3]*w[3];
    }
    s += be[u];
    s = fmaxf(s, 0.f);
    hL[u] = s;

    // ---- budR ----
    float udc = fminf(fmaxf(ud[u], -REC_MAXV), REC_MAXV);
    budR[(b << 8) + reord32(u)] = bd[u] + udc * s;

    // ---- boR (block 0 only) ----
    if (b == 0 && u < 128) boR[reord32(u)] = bo[u];

    // ---- weight frag packing (blocks 0..31) ----
    int gid = b * 256 + u;
    if (gid < 4096) {
        int f = gid >> 6, l = gid & 63;
        int ut = f >> 3, ks = f & 7;
        const float* src = Wd + (size_t)(ut * 32 + (l & 31)) * D_IN + ks * 16 + (l >> 5) * 8;
        int lo = pk8<false>(src[0], src[1], 0); lo = pk8<true>(src[2], src[3], lo);
        int hh = pk8<false>(src[4], src[5], 0); hh = pk8<true>(src[6], src[7], hh);
        *(int2v*)(WF8 + (size_t)gid * 8) = (int2v){lo, hh};
    } else if (gid < 8192) {
        int g = gid - 4096;
        int f = g >> 6, l = g & 63;
        int uk = f >> 2, dt = f & 3;
        const float* src = Wo + (size_t)(dt * 32 + (l & 31)) * U_H + uk * 16 + (l >> 5) * 8;
        int lo = pk8<false>(src[0], src[1], 0); lo = pk8<true>(src[2], src[3], lo);
        int hh = pk8<false>(src[4], src[5], 0); hh = pk8<true>(src[6], src[7], hh);
        *(int2v*)(WF8 + 32768 + (size_t)g * 8) = (int2v){lo, hh};
    }
    __syncthreads();

    // ---- t=0 loss term (threads 0..127 = output dim d) ----
    float v = 0.f;
    if (u < 128) {
        const f32x4* hr = (const f32x4*)hL;
        const f32x4* wo = (const f32x4*)(Wo + (size_t)u * U_H);
        float s2 = 0.f;
#pragma unroll
        for (int i = 0; i < 64; ++i) {
            f32x4 a = hr[i], w = wo[i];
            s2 += a[0]*w[0] + a[1]*w[1] + a[2]*w[2] + a[3]*w[3];
        }
        s2 += bo[u];
        float x = xs[((size_t)b * T_LEN + T_LEN - 1) * D_IN + u];
        float diff = x - s2;
        v = diff * diff;
    }
#pragma unroll
    for (int o = 32; o > 0; o >>= 1) v += __shfl_down(v, o);
    if (u == 0) red[0] = v;
    if (u == 64) red[1] = v;
    __syncthreads();
    if (u == 0) part2[b] = red[0] + red[1];
}

// ---- ph1pair: one ut for BOTH tiles. Weight+bias reads shared (halved) ------
__device__ __forceinline__ void ph1pair(const char* lds, const float* budL,
        int lane, int hi, int ut,
        i64 a0, i64 a1, i64 a2, i64 a3, i64 a4, i64 a5, i64 a6, i64 a7,
        i64 b0, i64 b1, i64 b2, i64 b3, i64 b4, i64 b5, i64 b6, i64 b7,
        i64& dAlo, i64& dAhi, i64& dBlo, i64& dBhi) {
    f32x16 cA, cB;
#pragma unroll
    for (int i = 0; i < 16; ++i) { cA[i] = 0.f; cB[i] = 0.f; }
    const int base = (ut * 8) << 9;
#define W_STEP(K, XA, XB)                                                       \
    {   i64 w = *(const i64*)(lds + base + (K << 9) + (lane << 3));             \
        cA = __builtin_amdgcn_mfma_f32_32x32x16_fp8_fp8(w, XA, cA, 0, 0, 0);    \
        cB = __builtin_amdgcn_mfma_f32_32x32x16_fp8_fp8(w, XB, cB, 0, 0, 0); }
    W_STEP(0, a0, b0) W_STEP(1, a1, b1) W_STEP(2, a2, b2) W_STEP(3, a3, b3)
    W_STEP(4, a4, b4) W_STEP(5, a5, b5) W_STEP(6, a6, b6) W_STEP(7, a7, b7)
#undef W_STEP
    const float* bp = budL + ut * 32 + hi * 16;
#pragma unroll
    for (int q = 0; q < 4; ++q) {
        f32x4 bq = *(const f32x4*)(bp + q * 4);
#pragma unroll
        for (int j = 0; j < 4; ++j) {
            cA[q * 4 + j] = fmaxf(cA[q * 4 + j] + bq[j], 0.f);
            cB[q * 4 + j] = fmaxf(cB[q * 4 + j] + bq[j], 0.f);
        }
    }
    {
        int d0 = pk8<false>(cA[0],  cA[1],  0); d0 = pk8<true>(cA[2],  cA[3],  d0);
        int d1 = pk8<false>(cA[4],  cA[5],  0); d1 = pk8<true>(cA[6],  cA[7],  d1);
        int d2 = pk8<false>(cA[8],  cA[9],  0); d2 = pk8<true>(cA[10], cA[11], d2);
        int d3 = pk8<false>(cA[12], cA[13], 0); d3 = pk8<true>(cA[14], cA[15], d3);
        int2v s = __builtin_amdgcn_permlane32_swap(d0, d1, false, false);
        int2v t = __builtin_amdgcn_permlane32_swap(d2, d3, false, false);
        dAlo = __builtin_bit_cast(i64, s);
        dAhi = __builtin_bit_cast(i64, t);
    }
    {
        int d0 = pk8<false>(cB[0],  cB[1],  0); d0 = pk8<true>(cB[2],  cB[3],  d0);
        int d1 = pk8<false>(cB[4],  cB[5],  0); d1 = pk8<true>(cB[6],  cB[7],  d1);
        int d2 = pk8<false>(cB[8],  cB[9],  0); d2 = pk8<true>(cB[10], cB[11], d2);
        int d3 = pk8<false>(cB[12], cB[13], 0); d3 = pk8<true>(cB[14], cB[15], d3);
        int2v s = __builtin_amdgcn_permlane32_swap(d0, d1, false, false);
        int2v t = __builtin_amdgcn_permlane32_swap(d2, d3, false, false);
        dBlo = __builtin_bit_cast(i64, s);
        dBhi = __builtin_bit_cast(i64, t);
    }
    __builtin_amdgcn_sched_barrier(0);
}

// ---------------- kernel 1: main fused pipeline (fp8, tile-PAIR/wave) --------
// 1024 blocks x 256 threads (4 waves). Each wave: 2 tiles of 32 rows (64 rows).
// Every weight ds_read feeds TWO MFMAs (tile A+B) -> LDS cycles/tile halved;
// bud/bo reads + addressing shared. 32 X-loads issued at pair start (2x mem
// parallelism). All state in named scalars.
__global__ __launch_bounds__(256, 2) void k_main(
        const float* __restrict__ xs, const float* __restrict__ budR,
        const float* __restrict__ boR, const char* __restrict__ WF8,
        float* __restrict__ part) {
    __shared__ __align__(16) char lds[67200];
    const int tid = threadIdx.x;

    // stage 64KB fp8 weight frags + 1KB budR(b) + 512B boR
    for (int i = tid; i < 4096; i += 256)
        ((f32x4*)lds)[i] = ((const f32x4*)WF8)[i];
    const int b = blockIdx.x >> 4;          // 16 blocks per batch-entry
    if (tid < 64) ((f32x4*)(lds + 65536))[tid] = ((const f32x4*)(budR + b * 256))[tid];
    else if (tid < 96) ((f32x4*)(lds + 66560))[tid - 64] = ((const f32x4*)boR)[tid - 64];
    __syncthreads();

    const int wave = tid >> 6, lane = tid & 63;
    const int m = lane & 31, hi = lane >> 5;
    const float* xsb = xs + ((size_t)b << 19);
    const float* budL = (const float*)(lds + 65536);
    const float* boL  = (const float*)(lds + 66560);
    float* wsumf = (float*)(lds + 67072);

    const int pair = blockIdx.x * 4 + wave;   // 0..4095
    const int t0 = (pair & 63) << 6;          // 64 rows per pair

    // ---- X rows (both tiles) -> fp8 B-frags (16 named i64) ----
    const float* xrA = xsb + (size_t)(t0 + m) * 128 + hi * 8;
    const float* xrB = xsb + (size_t)(t0 + 32 + m) * 128 + hi * 8;
    i64 xa0, xa1, xa2, xa3, xa4, xa5, xa6, xa7;
    i64 xb0, xb1, xb2, xb3, xb4, xb5, xb6, xb7;
#define LDX(PTR, KS, XV)                                                  \
    {   f32x4 v0 = *(const f32x4*)(PTR + KS * 16);                        \
        f32x4 v1 = *(const f32x4*)(PTR + KS * 16 + 4);                    \
        int lo = pk8<false>(v0[0], v0[1], 0); lo = pk8<true>(v0[2], v0[3], lo); \
        int hh = pk8<false>(v1[0], v1[1], 0); hh = pk8<true>(v1[2], v1[3], hh); \
        XV = __builtin_bit_cast(i64, (int2v){lo, hh}); }
    LDX(xrA, 0, xa0) LDX(xrA, 1, xa1) LDX(xrA, 2, xa2) LDX(xrA, 3, xa3)
    LDX(xrA, 4, xa4) LDX(xrA, 5, xa5) LDX(xrA, 6, xa6) LDX(xrA, 7, xa7)
    LDX(xrB, 0, xb0) LDX(xrB, 1, xb1) LDX(xrB, 2, xb2) LDX(xrB, 3, xb3)
    LDX(xrB, 4, xb4) LDX(xrB, 5, xb5) LDX(xrB, 6, xb6) LDX(xrB, 7, xb7)
#undef LDX

    // ---- Phase 1: 8 ut-steps, both tiles -> dec frags (32 named i64) ----
    i64 dA0a, dA0b, dA1a, dA1b, dA2a, dA2b, dA3a, dA3b;
    i64 dA4a, dA4b, dA5a, dA5b, dA6a, dA6b, dA7a, dA7b;
    i64 dB0a, dB0b, dB1a, dB1b, dB2a, dB2b, dB3a, dB3b;
    i64 dB4a, dB4b, dB5a, dB5b, dB6a, dB6b, dB7a, dB7b;
#define PH1(UT, DAL, DAH, DBL, DBH)                                       \
    ph1pair(lds, budL, lane, hi, UT,                                      \
            xa0, xa1, xa2, xa3, xa4, xa5, xa6, xa7,                       \
            xb0, xb1, xb2, xb3, xb4, xb5, xb6, xb7, DAL, DAH, DBL, DBH);
    PH1(0, dA0a, dA0b, dB0a, dB0b)
    PH1(1, dA1a, dA1b, dB1a, dB1b)
    PH1(2, dA2a, dA2b, dB2a, dB2b)
    PH1(3, dA3a, dA3b, dB3a, dB3b)
    PH1(4, dA4a, dA4b, dB4a, dB4b)
    PH1(5, dA5a, dA5b, dB5a, dB5b)
    PH1(6, dA6a, dA6b, dB6a, dB6b)
    PH1(7, dA7a, dA7b, dB7a, dB7b)
#undef PH1

    // ---- Phase 2 per d-tile (dt=0..3) + fused loss epilogue ----
    const int tA = t0 + m;                    // tile A row; tile B row = tA+32>0
    const float selA = (tA > 0) ? 1.f : 0.f;
    const float* trowA = xsb + (size_t)((tA > 0) ? tA - 1 : 0) * 128;
    const float* trowB = xsb + (size_t)(tA + 31) * 128;
    float lacc = 0.f;

#pragma unroll
    for (int dt = 0; dt < 4; ++dt) {
        f32x16 oA, oB;
#pragma unroll
        for (int i = 0; i < 16; ++i) { oA[i] = 0.f; oB[i] = 0.f; }
#define P2(UK, DA, DB)                                                    \
        {   i64 w = *(const i64*)(lds + 32768 + (((UK) * 4 + dt) << 9) + (lane << 3)); \
            oA = __builtin_amdgcn_mfma_f32_32x32x16_fp8_fp8(w, DA, oA, 0, 0, 0);       \
            oB = __builtin_amdgcn_mfma_f32_32x32x16_fp8_fp8(w, DB, oB, 0, 0, 0); }
        P2( 0, dA0a, dB0a) P2( 1, dA0b, dB0b)
        P2( 2, dA1a, dB1a) P2( 3, dA1b, dB1b)
        P2( 4, dA2a, dB2a) P2( 5, dA2b, dB2b)
        P2( 6, dA3a, dB3a) P2( 7, dA3b, dB3b)
        P2( 8, dA4a, dB4a) P2( 9, dA4b, dB4b)
        P2(10, dA5a, dB5a) P2(11, dA5b, dB5b)
        P2(12, dA6a, dB6a) P2(13, dA6b, dB6b)
        P2(14, dA7a, dB7a) P2(15, dA7b, dB7b)
#undef P2
        __builtin_amdgcn_sched_barrier(0);
#pragma unroll
        for (int q = 0; q < 4; ++q) {
            f32x4 bv  = *(const f32x4*)(boL + dt * 32 + hi * 16 + q * 4);
            f32x4 tgA = *(const f32x4*)(trowA + dt * 32 + q * 8 + hi * 4);
            f32x4 tgB = *(const f32x4*)(trowB + dt * 32 + q * 8 + hi * 4);
#pragma unroll
            for (int j = 0; j < 4; ++j) {
                float ovA = oA[q * 4 + j] + bv[j];
                float ovB = oB[q * 4 + j] + bv[j];
                float dA = tgA[j] - ovA;
                float dB = tgB[j] - ovB;
                lacc += selA * dA * dA + dB * dB;
            }
        }
    }

    // ---- block-level reduction: ONE store per block, no atomic ----
#pragma unroll
    for (int o = 32; o > 0; o >>= 1) lacc += __shfl_down(lacc, o);
    if (lane == 0) wsumf[wave] = lacc;
    __syncthreads();
    if (tid == 0) {
        float s = 0.f;
#pragma unroll
        for (int i = 0; i < 4; ++i) s += wsumf[i];
        part[blockIdx.x] = s;
    }
}

// ---------------- kernel 2: final reduction (plain store, no atomic) ---------
__global__ void k_final(const float* __restrict__ part, const float* __restrict__ part2,
                        float* __restrict__ loss) {
    __shared__ float ws[16];
    const int tid = threadIdx.x;   // 1024
    float v = part[tid];
    if (tid < 64) v += part2[tid];
#pragma unroll
    for (int o = 32; o > 0; o >>= 1) v += __shfl_down(v, o);
    if ((tid & 63) == 0) ws[tid >> 6] = v;
    __syncthreads();
    if (tid == 0) {
        float s = 0.f;
#pragma unroll
        for (int i = 0; i < 16; ++i) s += ws[i];
        *loss = s * (1.f / 262144.f);
    }
}

extern "C" void kernel_launch(void* const* d_in, const int* in_sizes, int n_in,
                              void* d_out, int out_size, void* d_ws, size_t ws_size,
                              hipStream_t stream) {
    const float* xs = (const float*)d_in[0];
    const float* We = (const float*)d_in[1];
    const float* be = (const float*)d_in[2];
    // d_in[3] = ue (unused: encoder hidden state is always zero)
    const float* Wd = (const float*)d_in[4];
    const float* bd = (const float*)d_in[5];
    const float* ud = (const float*)d_in[6];
    const float* Wo = (const float*)d_in[7];
    const float* bo = (const float*)d_in[8];
    float* loss = (float*)d_out;

    char* ws = (char*)d_ws;
    float* budR  = (float*)(ws);             // 65536 B
    char*  WF8   = (char*)(ws + 65536);      // 65536 B (Wd frags, then Wo frags)
    float* boR   = (float*)(ws + 131072);    // 512 B
    float* part  = (float*)(ws + 131584);    // 4096 B (1024 block partials)
    float* part2 = (float*)(ws + 135680);    // 256 B  (64 loss0 partials)

    k_pre<<<64, 256, 0, stream>>>(xs, We, be, Wd, bd, ud, Wo, bo,
                                  budR, boR, WF8, part2);
    k_main<<<1024, 256, 0, stream>>>(xs, budR, boR, WF8, part);
    k_final<<<1, 1024, 0, stream>>>(part, part2, loss);
}